// Round 10
// baseline (216.482 us; speedup 1.0000x reference)
//
#include <hip/hip_runtime.h>

typedef _Float16 f16;
typedef _Float16 f16x4 __attribute__((ext_vector_type(4)));
typedef _Float16 f16x8 __attribute__((ext_vector_type(8)));
typedef float f32x4 __attribute__((ext_vector_type(4)));

#define MFMA16(a, b, c) __builtin_amdgcn_mfma_f32_16x16x32_f16(a, b, c, 0, 0, 0)
#define QSCALE 11.5415603f   /* 8 * log2(e): folds the reference's x8 scale + exp2 domain */

typedef const __attribute__((address_space(1))) void* gp1_t;
typedef __attribute__((address_space(3))) void* lp3_t;
__device__ __forceinline__ void gld16(const void* g, void* l) {
    __builtin_amdgcn_global_load_lds((gp1_t)g, (lp3_t)l, 16, 0, 0);
}

// ---------------------------------------------------------------- fused fp32->fp16 converts
__global__ __launch_bounds__(256) void cvt_all(
    const float* __restrict__ x, const float* __restrict__ wq, const float* __restrict__ wp,
    f16* __restrict__ xh, f16* __restrict__ wqh, f16* __restrict__ wph)
{
    int i = blockIdx.x * 256 + threadIdx.x;          // float4 index, total 2097152 exact
    const float4* src; f16x4* dst; int off;
    if (i < 1048576)      { src = (const float4*)x;  dst = (f16x4*)xh;  off = i; }
    else if (i < 1835008) { src = (const float4*)wq; dst = (f16x4*)wqh; off = i - 1048576; }
    else                  { src = (const float4*)wp; dst = (f16x4*)wph; off = i - 1835008; }
    float4 v = src[off];
    f16x4 o = { (f16)v.x, (f16)v.y, (f16)v.z, (f16)v.w };
    dst[off] = o;
}

// ---------------------------------------------------------------- GEMM C = A @ B^T (m97 structure)
template<int EPI, int BN>
__global__ __launch_bounds__(256) void gemm_k(
    const f16* __restrict__ A, const f16* __restrict__ B, int K,
    f16* __restrict__ qb, f16* __restrict__ kb, f16* __restrict__ vt,
    float* __restrict__ outF, const float* __restrict__ bias)
{
    __shared__ f16 as[128 * 32];
    __shared__ f16 bs[BN * 32];
    constexpr int WN = BN / 2;
    constexpr int NT = BN / 32;
    const int t = threadIdx.x;
    const int bidf = blockIdx.y * gridDim.x + blockIdx.x;
    const int cpx  = (gridDim.x * gridDim.y) >> 3;
    const int swz  = (bidf & 7) * cpx + (bidf >> 3);
    const int m0 = (swz / gridDim.x) * 128, n0 = (swz % gridDim.x) * BN;
    const int lane = t & 63, wv = t >> 6;
    const int wm = wv >> 1, wn = wv & 1;
    const int lr = lane & 15, g = lane >> 4;
    const int srow = lane >> 2, schk = (lane & 3) * 8;
    const f16* Ab = A + (size_t)m0 * K;
    const f16* Bb = B + (size_t)n0 * K;
    f32x4 acc[4][NT] = {};

    for (int k0 = 0; k0 < K; k0 += 32) {
        __syncthreads();
        #pragma unroll
        for (int i2 = 0; i2 < 2; ++i2) {
            const int r0 = wv * 32 + i2 * 16;
            gld16(&Ab[(size_t)(r0 + srow) * K + k0 + schk], &as[r0 * 32]);
        }
        if constexpr (BN == 128) {
            #pragma unroll
            for (int i2 = 0; i2 < 2; ++i2) {
                const int r0 = wv * 32 + i2 * 16;
                gld16(&Bb[(size_t)(r0 + srow) * K + k0 + schk], &bs[r0 * 32]);
            }
        } else {
            const int r0 = wv * 16;
            gld16(&Bb[(size_t)(r0 + srow) * K + k0 + schk], &bs[r0 * 32]);
        }
        __syncthreads();
        f16x8 af[4], bf[NT];
        #pragma unroll
        for (int mt = 0; mt < 4; ++mt)
            af[mt] = *reinterpret_cast<const f16x8*>(&as[(wm * 64 + mt * 16 + lr) * 32 + g * 8]);
        #pragma unroll
        for (int nt = 0; nt < NT; ++nt)
            bf[nt] = *reinterpret_cast<const f16x8*>(&bs[(wn * WN + nt * 16 + lr) * 32 + g * 8]);
        #pragma unroll
        for (int mt = 0; mt < 4; ++mt)
            #pragma unroll
            for (int nt = 0; nt < NT; ++nt)
                acc[mt][nt] = MFMA16(af[mt], bf[nt], acc[mt][nt]);
    }

    #pragma unroll
    for (int mt = 0; mt < 4; ++mt) {
        #pragma unroll
        for (int nt = 0; nt < NT; ++nt) {
            const int n = n0 + wn * WN + nt * 16 + lr;
            const int s0 = m0 + wm * 64 + mt * 16 + 4 * g;
            if (EPI == 0) {
                const int which = n >> 10, h = (n >> 6) & 15, d = n & 63;
                const int b = s0 >> 11, s = s0 & 2047;
                if (which == 2) {
                    f16x4 vv;
                    #pragma unroll
                    for (int i = 0; i < 4; ++i) vv[i] = (f16)acc[mt][nt][i];
                    *reinterpret_cast<f16x4*>(&vt[((size_t)((b << 4) + h) * 64 + d) * 2048 + s]) = vv;
                } else {
                    f16* dst = which ? kb : qb;
                    const float sc = which ? 1.0f : QSCALE;
                    #pragma unroll
                    for (int i = 0; i < 4; ++i)
                        dst[((size_t)((b << 4) + h) * 2048 + (s + i)) * 64 + d] = (f16)(acc[mt][nt][i] * sc);
                }
            } else {
                #pragma unroll
                for (int i = 0; i < 4; ++i)
                    outF[(size_t)(s0 + i) * 1024 + n] = acc[mt][nt][i] + bias[n];
            }
        }
    }
}

// ---------------------------------------------------------------- flash attention v7
// 4-wave blocks share K/V tiles via LDS (gld16, linear dest + XOR-pre-swizzled global src,
// rule #21). Block = group g: q-units {4g..4g+3} of one bh; wave w owns unit 4g+w (64 rows,
// 4 nt chains). 2-phase: stage t+1 -> consume t -> __syncthreads (drains vmcnt).
// Groups g>=4 split kv into 3 chunks -> 16 blocks/bh x 32 bh = 512 blocks = 2/CU.
// Split chunks write normalized partials (m,l,O/l) -> combine_k.
__global__ __launch_bounds__(256) void attn_k(
    const f16* __restrict__ Q, const f16* __restrict__ K, const f16* __restrict__ VT,
    f16* __restrict__ ctx, f16* __restrict__ opart,
    float* __restrict__ mpart, float* __restrict__ lpart)
{
    __shared__ f16 kbuf[2][64 * 64];
    __shared__ f16 vbuf[2][64 * 64];
    __shared__ f16 lp[4][64][72];
    const int t = threadIdx.x, wv = t >> 6, lane = t & 63;
    const int lr = lane & 15, g = lane >> 4;
    const int bid = blockIdx.x;
    const int bh = bid & 31;
    const int rest = bid >> 5;             // 0..15, descending chunk length
    int grp, c;
    if (rest == 0)      { grp = 3; c = 0; }
    else if (rest == 1) { grp = 2; c = 0; }
    else if (rest < 8)  { grp = 7 - (rest - 2) / 3; c = (rest - 2) % 3; }
    else if (rest == 8) { grp = 1; c = 0; }
    else if (rest < 15) { grp = 5 - (rest - 9) / 3; c = (rest - 9) % 3; }
    else                { grp = 0; c = 0; }
    const int E  = 4 * grp + 4;            // group kv extent in tiles
    const int nc = (grp < 4) ? 1 : 3;
    const int cbase = E / nc, crem = E % nc;
    const int start = c * cbase + (c < crem ? c : crem);
    const int len   = cbase + (c < crem ? 1 : 0);
    const int end   = start + len;
    const int uw = 4 * grp + wv;           // this wave's q-unit
    const int q0 = uw << 6;
    const int myEnd = (uw + 1 < end) ? (uw + 1) : end;

    const int b = bh >> 4, h = bh & 15;
    const size_t base = (size_t)bh * (2048 * 64);
    const f16* Qb = Q + base;
    const f16* Kb = K + base;
    const f16* Vb = VT + base;             // [64][2048]

    f16x8 qf[4][2];
    #pragma unroll
    for (int nt = 0; nt < 4; ++nt)
        #pragma unroll
        for (int ks = 0; ks < 2; ++ks)
            qf[nt][ks] = *reinterpret_cast<const f16x8*>(&Qb[(size_t)(q0 + nt * 16 + lr) * 64 + ks * 32 + g * 8]);

    f32x4 o[4][4] = {};
    float mrun[4] = { -1e30f, -1e30f, -1e30f, -1e30f };
    float lsum[4] = { 0.f, 0.f, 0.f, 0.f };

    const int lrow8 = lane >> 3, lchk = lane & 7;   // staging decomposition

#define STAGE(TT, BSEL) do {                                                            \
    const int kv0s_ = (TT) << 6;                                                        \
    f16* kd_ = &kbuf[BSEL][0];                                                          \
    f16* vd_ = &vbuf[BSEL][0];                                                          \
    _Pragma("unroll")                                                                   \
    for (int i2 = 0; i2 < 2; ++i2) {                                                    \
        const int rr = wv * 16 + i2 * 8;          /* wave-uniform row base */           \
        const int krow = rr + lrow8;                                                    \
        gld16(&Kb[(size_t)(kv0s_ + krow) * 64 + ((lchk ^ (krow & 7)) * 8)],             \
              kd_ + rr * 64);                                                           \
        gld16(&Vb[(size_t)krow * 2048 + kv0s_ + ((lchk ^ (krow & 7)) * 8)],             \
              vd_ + rr * 64);                                                           \
    }                                                                                   \
} while (0)

#define TILE_BODY(BSEL, KV0, DIAGM) do {                                                \
    const int kv0_ = (KV0);                                                             \
    const f16* kc_ = &kbuf[BSEL][0];                                                    \
    const f16* vc_ = &vbuf[BSEL][0];                                                    \
    f32x4 st[4][4] = {};                                                                \
    _Pragma("unroll")                                                                   \
    for (int mt = 0; mt < 4; ++mt) {                                                    \
        const int r_ = mt * 16 + lr;                                                    \
        f16x8 ak[2];                                                                    \
        _Pragma("unroll")                                                               \
        for (int ks = 0; ks < 2; ++ks)                                                  \
            ak[ks] = *reinterpret_cast<const f16x8*>(                                   \
                &kc_[r_ * 64 + ((4 * ks + g) ^ (lr & 7)) * 8]);                         \
        _Pragma("unroll")                                                               \
        for (int nt = 0; nt < 4; ++nt)                                                  \
            if (!(DIAGM) || mt <= nt) {                                                 \
                _Pragma("unroll")                                                       \
                for (int ks = 0; ks < 2; ++ks)                                          \
                    st[mt][nt] = MFMA16(ak[ks], qf[nt][ks], st[mt][nt]);                \
            }                                                                           \
    }                                                                                   \
    _Pragma("unroll")                                                                   \
    for (int nt = 0; nt < 4; ++nt) {                                                    \
        float mloc = -1e30f;                                                            \
        _Pragma("unroll")                                                               \
        for (int mt = 0; mt < 4; ++mt) {                                                \
            if ((DIAGM) && mt > nt) continue;                                           \
            _Pragma("unroll")                                                           \
            for (int i = 0; i < 4; ++i) {                                               \
                float sv = st[mt][nt][i];                                               \
                if ((DIAGM) && mt == nt) {                                              \
                    sv = (4 * g + i <= lr) ? sv : -1e30f;                               \
                    st[mt][nt][i] = sv;                                                 \
                }                                                                       \
                mloc = fmaxf(mloc, sv);                                                 \
            }                                                                           \
        }                                                                               \
        mloc = fmaxf(mloc, __shfl_xor(mloc, 16));                                       \
        mloc = fmaxf(mloc, __shfl_xor(mloc, 32));                                       \
        if (__any(mloc > mrun[nt] + 8.0f)) {                                            \
            float mnew = fmaxf(mrun[nt], mloc);                                         \
            float sc = exp2f(mrun[nt] - mnew);                                          \
            lsum[nt] *= sc;                                                             \
            _Pragma("unroll")                                                           \
            for (int mo = 0; mo < 4; ++mo)                                              \
                _Pragma("unroll")                                                       \
                for (int i = 0; i < 4; ++i) o[mo][nt][i] *= sc;                         \
            mrun[nt] = mnew;                                                            \
        }                                                                               \
        float ls = 0.f;                                                                 \
        _Pragma("unroll")                                                               \
        for (int mt = 0; mt < 4; ++mt) {                                                \
            f16x4 pk;                                                                   \
            if ((DIAGM) && mt > nt) {                                                   \
                pk[0] = pk[1] = pk[2] = pk[3] = (f16)0.f;                               \
            } else {                                                                    \
                float p0 = exp2f(st[mt][nt][0] - mrun[nt]);                             \
                float p1 = exp2f(st[mt][nt][1] - mrun[nt]);                             \
                float p2 = exp2f(st[mt][nt][2] - mrun[nt]);                             \
                float p3 = exp2f(st[mt][nt][3] - mrun[nt]);                             \
                ls += (p0 + p1) + (p2 + p3);                                            \
                pk[0] = (f16)p0; pk[1] = (f16)p1; pk[2] = (f16)p2; pk[3] = (f16)p3;     \
            }                                                                           \
            *reinterpret_cast<f16x4*>(&lp[wv][nt * 16 + lr][mt * 16 + 4 * g]) = pk;     \
        }                                                                               \
        lsum[nt] += ls;                                                                 \
    }                                                                                   \
    {                                                                                   \
        f16x8 pf[4][2];                                                                 \
        _Pragma("unroll")                                                               \
        for (int nt = 0; nt < 4; ++nt)                                                  \
            _Pragma("unroll")                                                           \
            for (int ks = 0; ks < 2; ++ks)                                              \
                pf[nt][ks] = *reinterpret_cast<const f16x8*>(                           \
                    &lp[wv][nt * 16 + lr][ks * 32 + g * 8]);                            \
        _Pragma("unroll")                                                               \
        for (int mo = 0; mo < 4; ++mo) {                                                \
            const int d_ = mo * 16 + lr;                                                \
            f16x8 av[2];                                                                \
            _Pragma("unroll")                                                           \
            for (int ks = 0; ks < 2; ++ks)                                              \
                av[ks] = *reinterpret_cast<const f16x8*>(                               \
                    &vc_[d_ * 64 + ((4 * ks + g) ^ (lr & 7)) * 8]);                     \
            _Pragma("unroll")                                                           \
            for (int nt = 0; nt < 4; ++nt)                                              \
                _Pragma("unroll")                                                       \
                for (int ks = 0; ks < 2; ++ks)                                          \
                    o[mo][nt] = MFMA16(av[ks], pf[nt][ks], o[mo][nt]);                  \
        }                                                                               \
    }                                                                                   \
} while (0)

    // prologue: stage first tile
    if ((start & 1) == 0) STAGE(start, 0); else STAGE(start, 1);
    __syncthreads();

    for (int tt = start; tt < end; ++tt) {
        const int cur = tt & 1;
        if (tt + 1 < end) {
            if (cur) STAGE(tt + 1, 0); else STAGE(tt + 1, 1);
        }
        if (tt < myEnd) {
            if (tt == uw) {
                if (cur) TILE_BODY(1, tt << 6, 1); else TILE_BODY(0, tt << 6, 1);
            } else {
                if (cur) TILE_BODY(1, tt << 6, 0); else TILE_BODY(0, tt << 6, 0);
            }
        }
        __syncthreads();   // drains stage vmcnt; protects buffer reuse
    }
#undef STAGE
#undef TILE_BODY

    // epilogue
    const bool split = (nc > 1);
    #pragma unroll
    for (int nt = 0; nt < 4; ++nt) {
        float l = lsum[nt];
        l += __shfl_xor(l, 16);
        l += __shfl_xor(l, 32);
        const float inv = 1.0f / l;
        const int lrow = nt * 16 + lr;
        if (!split) {
            const size_t rowoff = ((size_t)(b * 2048 + q0 + lrow)) * 1024 + h * 64;
            #pragma unroll
            for (int mo = 0; mo < 4; ++mo) {
                f16x4 ov;
                #pragma unroll
                for (int i2 = 0; i2 < 4; ++i2) ov[i2] = (f16)(o[mo][nt][i2] * inv);
                *reinterpret_cast<f16x4*>(&ctx[rowoff + mo * 16 + 4 * g]) = ov;
            }
        } else {
            const int slot = bh * 12 + (grp - 4) * 3 + c;
            const int mi = slot * 256 + wv * 64 + lrow;
            #pragma unroll
            for (int mo = 0; mo < 4; ++mo) {
                f16x4 ov;
                #pragma unroll
                for (int i2 = 0; i2 < 4; ++i2) ov[i2] = (f16)(o[mo][nt][i2] * inv);
                *reinterpret_cast<f16x4*>(&opart[(size_t)mi * 64 + mo * 16 + 4 * g]) = ov;
            }
            if (g == 0) { mpart[mi] = mrun[nt]; lpart[mi] = l; }
        }
    }
}

// ---------------------------------------------------------------- combine partials -> ctx
// 512 blocks = (bh 32) x (u 16..31); nc = 3 always. 256 threads: lrow=t>>2, seg=t&3.
__global__ __launch_bounds__(256) void combine_k(
    const f16* __restrict__ opart, const float* __restrict__ mpart,
    const float* __restrict__ lpart, f16* __restrict__ ctx)
{
    const int blk = blockIdx.x;
    const int bh = blk & 31, u = 16 + (blk >> 5);
    const int b = bh >> 4, h = bh & 15;
    const int grp = u >> 2;                            // 4..7
    const int slot0 = bh * 12 + (grp - 4) * 3;
    const int rowbase = (u & 3) * 64;
    const int t = threadIdx.x;
    const int lrow = t >> 2, seg = t & 3;

    float m[3], l[3], w[3];
    float M = -1e30f;
    #pragma unroll
    for (int cc = 0; cc < 3; ++cc) {
        m[cc] = mpart[(slot0 + cc) * 256 + rowbase + lrow];
        l[cc] = lpart[(slot0 + cc) * 256 + rowbase + lrow];
        M = fmaxf(M, m[cc]);
    }
    float wsum = 0.f;
    #pragma unroll
    for (int cc = 0; cc < 3; ++cc) { w[cc] = l[cc] * exp2f(m[cc] - M); wsum += w[cc]; }
    const float r = 1.0f / wsum;

    float acc[16] = {};
    #pragma unroll
    for (int cc = 0; cc < 3; ++cc) {
        const float coef = w[cc] * r;
        const size_t rb = (size_t)((slot0 + cc) * 256 + rowbase + lrow) * 64 + seg * 16;
        f16x8 v0 = *reinterpret_cast<const f16x8*>(&opart[rb]);
        f16x8 v1 = *reinterpret_cast<const f16x8*>(&opart[rb + 8]);
        #pragma unroll
        for (int i = 0; i < 8; ++i) { acc[i] += coef * (float)v0[i]; acc[i + 8] += coef * (float)v1[i]; }
    }
    f16x8 o0, o1;
    #pragma unroll
    for (int i = 0; i < 8; ++i) { o0[i] = (f16)acc[i]; o1[i] = (f16)acc[i + 8]; }
    const size_t wb = ((size_t)(b * 2048 + u * 64 + lrow)) * 1024 + h * 64 + seg * 16;
    *reinterpret_cast<f16x8*>(&ctx[wb]) = o0;
    *reinterpret_cast<f16x8*>(&ctx[wb + 8]) = o1;
}

// ---------------------------------------------------------------- launch
extern "C" void kernel_launch(void* const* d_in, const int* in_sizes, int n_in,
                              void* d_out, int out_size, void* d_ws, size_t ws_size,
                              hipStream_t stream) {
    const float* x      = (const float*)d_in[0];   // [2,2048,1024]
    const float* w_qkv  = (const float*)d_in[1];   // [3072,1024]
    const float* w_proj = (const float*)d_in[2];   // [1024,1024]
    const float* b_proj = (const float*)d_in[3];   // [1024]
    float* out = (float*)d_out;                    // [2,2048,1024] fp32

    char* p = (char*)d_ws;
    f16* xh     = (f16*)p; p += (size_t)4096 * 1024 * 2;        // 8 MB (reused: m/l partials)
    f16* wqkvh  = (f16*)p; p += (size_t)3072 * 1024 * 2;        // 6 MB
    f16* wprojh = (f16*)p; p += (size_t)1024 * 1024 * 2;        // 2 MB (live through gemm1)
    f16* qbuf   = (f16*)p; p += (size_t)2 * 16 * 2048 * 64 * 2; // 8 MB  [B,H,S,64], pre-scaled
    f16* kbuf   = (f16*)p; p += (size_t)2 * 16 * 2048 * 64 * 2; // 8 MB  [B,H,S,64]
    f16* vtbuf  = (f16*)p; p += (size_t)2 * 16 * 64 * 2048 * 2; // 8 MB  [B,H,64,S] transposed
    f16* ctx    = (f16*)p; p += (size_t)4096 * 1024 * 2;        // 8 MB  (total 48 MB)

    // Partial O lives in d_out (dead until gemm1 overwrites it):
    // 32 bh x 12 slots x 256 rows x 128 B = 12.58 MB <= 16.78 MB.
    f16*   opart = (f16*)d_out;
    float* mpart = (float*)xh;               // 98304 f32
    float* lpart = mpart + 98304;            // 98304 f32

    cvt_all<<<8192, 256, 0, stream>>>(x, w_qkv, w_proj, xh, wqkvh, wprojh);

    gemm_k<0, 128><<<dim3(24, 32), 256, 0, stream>>>(xh, wqkvh, 1024, qbuf, kbuf, vtbuf, nullptr, nullptr);

    attn_k<<<512, 256, 0, stream>>>(qbuf, kbuf, vtbuf, ctx, opart, mpart, lpart);

    combine_k<<<512, 256, 0, stream>>>(opart, mpart, lpart, ctx);

    gemm_k<1, 64><<<dim3(16, 32), 256, 0, stream>>>(ctx, wprojh, 1024, nullptr, nullptr, nullptr, out, b_proj);
}

// Round 11
// 210.113 us; speedup vs baseline: 1.0303x; 1.0303x over previous
//
#include <hip/hip_runtime.h>

typedef _Float16 f16;
typedef _Float16 f16x4 __attribute__((ext_vector_type(4)));
typedef _Float16 f16x8 __attribute__((ext_vector_type(8)));
typedef float f32x4 __attribute__((ext_vector_type(4)));

#define MFMA16(a, b, c) __builtin_amdgcn_mfma_f32_16x16x32_f16(a, b, c, 0, 0, 0)
#define QSCALE 11.5415603f   /* 8 * log2(e): folds the reference's x8 scale + exp2 domain */

typedef const __attribute__((address_space(1))) void* gp1_t;
typedef __attribute__((address_space(3))) void* lp3_t;
__device__ __forceinline__ void gld16(const void* g, void* l) {
    __builtin_amdgcn_global_load_lds((gp1_t)g, (lp3_t)l, 16, 0, 0);
}

// slot prefix over split units (u>=10): nc(u) = ceil((u+1)/5) = (u+5)/5
__device__ __forceinline__ int unit_psl(int u) {
    return (u < 15) ? 3 * (u - 10)
         : (u < 20) ? 15 + 4 * (u - 15)
         : (u < 25) ? 35 + 5 * (u - 20)
         : (u < 30) ? 60 + 6 * (u - 25)
         :            90 + 7 * (u - 30);
}

// ---------------------------------------------------------------- fused fp32->fp16 converts
__global__ __launch_bounds__(256) void cvt_all(
    const float* __restrict__ x, const float* __restrict__ wq, const float* __restrict__ wp,
    f16* __restrict__ xh, f16* __restrict__ wqh, f16* __restrict__ wph)
{
    int i = blockIdx.x * 256 + threadIdx.x;          // float4 index, total 2097152 exact
    const float4* src; f16x4* dst; int off;
    if (i < 1048576)      { src = (const float4*)x;  dst = (f16x4*)xh;  off = i; }
    else if (i < 1835008) { src = (const float4*)wq; dst = (f16x4*)wqh; off = i - 1048576; }
    else                  { src = (const float4*)wp; dst = (f16x4*)wph; off = i - 1835008; }
    float4 v = src[off];
    f16x4 o = { (f16)v.x, (f16)v.y, (f16)v.z, (f16)v.w };
    dst[off] = o;
}

// ---------------------------------------------------------------- GEMM C = A @ B^T (m97 structure)
template<int EPI, int BN>
__global__ __launch_bounds__(256) void gemm_k(
    const f16* __restrict__ A, const f16* __restrict__ B, int K,
    f16* __restrict__ qb, f16* __restrict__ kb, f16* __restrict__ vt,
    float* __restrict__ outF, const float* __restrict__ bias)
{
    __shared__ f16 as[128 * 32];
    __shared__ f16 bs[BN * 32];
    constexpr int WN = BN / 2;
    constexpr int NT = BN / 32;
    const int t = threadIdx.x;
    const int bidf = blockIdx.y * gridDim.x + blockIdx.x;
    const int cpx  = (gridDim.x * gridDim.y) >> 3;
    const int swz  = (bidf & 7) * cpx + (bidf >> 3);
    const int m0 = (swz / gridDim.x) * 128, n0 = (swz % gridDim.x) * BN;
    const int lane = t & 63, wv = t >> 6;
    const int wm = wv >> 1, wn = wv & 1;
    const int lr = lane & 15, g = lane >> 4;
    const int srow = lane >> 2, schk = (lane & 3) * 8;
    const f16* Ab = A + (size_t)m0 * K;
    const f16* Bb = B + (size_t)n0 * K;
    f32x4 acc[4][NT] = {};

    for (int k0 = 0; k0 < K; k0 += 32) {
        __syncthreads();
        #pragma unroll
        for (int i2 = 0; i2 < 2; ++i2) {
            const int r0 = wv * 32 + i2 * 16;
            gld16(&Ab[(size_t)(r0 + srow) * K + k0 + schk], &as[r0 * 32]);
        }
        if constexpr (BN == 128) {
            #pragma unroll
            for (int i2 = 0; i2 < 2; ++i2) {
                const int r0 = wv * 32 + i2 * 16;
                gld16(&Bb[(size_t)(r0 + srow) * K + k0 + schk], &bs[r0 * 32]);
            }
        } else {
            const int r0 = wv * 16;
            gld16(&Bb[(size_t)(r0 + srow) * K + k0 + schk], &bs[r0 * 32]);
        }
        __syncthreads();
        f16x8 af[4], bf[NT];
        #pragma unroll
        for (int mt = 0; mt < 4; ++mt)
            af[mt] = *reinterpret_cast<const f16x8*>(&as[(wm * 64 + mt * 16 + lr) * 32 + g * 8]);
        #pragma unroll
        for (int nt = 0; nt < NT; ++nt)
            bf[nt] = *reinterpret_cast<const f16x8*>(&bs[(wn * WN + nt * 16 + lr) * 32 + g * 8]);
        #pragma unroll
        for (int mt = 0; mt < 4; ++mt)
            #pragma unroll
            for (int nt = 0; nt < NT; ++nt)
                acc[mt][nt] = MFMA16(af[mt], bf[nt], acc[mt][nt]);
    }

    #pragma unroll
    for (int mt = 0; mt < 4; ++mt) {
        #pragma unroll
        for (int nt = 0; nt < NT; ++nt) {
            const int n = n0 + wn * WN + nt * 16 + lr;
            const int s0 = m0 + wm * 64 + mt * 16 + 4 * g;
            if (EPI == 0) {
                const int which = n >> 10, h = (n >> 6) & 15, d = n & 63;
                const int b = s0 >> 11, s = s0 & 2047;
                if (which == 2) {
                    f16x4 vv;
                    #pragma unroll
                    for (int i = 0; i < 4; ++i) vv[i] = (f16)acc[mt][nt][i];
                    *reinterpret_cast<f16x4*>(&vt[((size_t)((b << 4) + h) * 64 + d) * 2048 + s]) = vv;
                } else {
                    f16* dst = which ? kb : qb;
                    const float sc = which ? 1.0f : QSCALE;
                    #pragma unroll
                    for (int i = 0; i < 4; ++i)
                        dst[((size_t)((b << 4) + h) * 2048 + (s + i)) * 64 + d] = (f16)(acc[mt][nt][i] * sc);
                }
            } else {
                #pragma unroll
                for (int i = 0; i < 4; ++i)
                    outF[(size_t)(s0 + i) * 1024 + n] = acc[mt][nt][i] + bias[n];
            }
        }
    }
}

// ---------------------------------------------------------------- flash attention v8
// = measured v6 fat-wave structure (QBLK=64/wave, 1-wave blocks, no barriers) with finer
// kv chunking: unit u (rows [64u,64u+64), ntt=u+1 tiles) split into nc=ceil(ntt/5) chunks
// (<=5 tiles each) for u>=10; 114 chunks/bh x 32 bh = 3648 blocks (3.6 waves/SIMD).
// Split chunks write normalized partials (m, l, O/l f16) into 3 recycled regions.
__global__ __launch_bounds__(64, 2) void attn_k(
    const f16* __restrict__ Q, const f16* __restrict__ K, const f16* __restrict__ VT,
    f16* __restrict__ ctx, f16* __restrict__ op0, f16* __restrict__ op1, f16* __restrict__ op2,
    float* __restrict__ mpart, float* __restrict__ lpart)
{
    __shared__ f16 lp[64][72];
    const int lane = threadIdx.x;
    const int lr = lane & 15, g = lane >> 4;
    const int bid = blockIdx.x;
    const int bh = bid & 31;               // low bits -> stable XCD per bh (K/V L2 locality)
    const int rest = bid >> 5;             // 0..113, descending u (longest chunks first)
    int u, c;
    if (rest < 14)       { u = 31 - rest / 7;          c = rest % 7; }
    else if (rest < 44)  { u = 29 - (rest - 14) / 6;   c = (rest - 14) % 6; }
    else if (rest < 69)  { u = 24 - (rest - 44) / 5;   c = (rest - 44) % 5; }
    else if (rest < 89)  { u = 19 - (rest - 69) / 4;   c = (rest - 69) % 4; }
    else if (rest < 104) { u = 14 - (rest - 89) / 3;   c = (rest - 89) % 3; }
    else                 { u = 9 - (rest - 104);       c = 0; }
    const int ntt = u + 1;
    const int nc  = (u < 10) ? 1 : (u + 5) / 5;
    const int cbase = ntt / nc, crem = ntt % nc;
    const int start = c * cbase + (c < crem ? c : crem);
    const int len   = cbase + (c < crem ? 1 : 0);
    const bool diag = (start + len == ntt);

    const int b = bh >> 4, h = bh & 15;
    const size_t base = (size_t)bh * (2048 * 64);
    const f16* Qb = Q + base;
    const f16* Kb = K + base;
    const f16* Vb = VT + base;             // [64][2048]
    const int q0 = u << 6;

    f16x8 qf[4][2];
    #pragma unroll
    for (int nt = 0; nt < 4; ++nt)
        #pragma unroll
        for (int ks = 0; ks < 2; ++ks)
            qf[nt][ks] = *reinterpret_cast<const f16x8*>(&Qb[(size_t)(q0 + nt * 16 + lr) * 64 + ks * 32 + g * 8]);

    f32x4 o[4][4] = {};                    // o[mo(d)][nt(q)]
    float mrun[4] = { -1e30f, -1e30f, -1e30f, -1e30f };
    float lsum[4] = { 0.f, 0.f, 0.f, 0.f };

#define ATTN_TILE(KV0, DIAGM) do {                                                      \
    const int kv0_ = (KV0);                                                             \
    f32x4 st[4][4] = {};                                                                \
    _Pragma("unroll")                                                                   \
    for (int mt = 0; mt < 4; ++mt) {                                                    \
        f16x8 ak[2];                                                                    \
        _Pragma("unroll")                                                               \
        for (int ks = 0; ks < 2; ++ks)                                                  \
            ak[ks] = *reinterpret_cast<const f16x8*>(                                   \
                &Kb[(size_t)(kv0_ + mt * 16 + lr) * 64 + ks * 32 + g * 8]);             \
        _Pragma("unroll")                                                               \
        for (int nt = 0; nt < 4; ++nt)                                                  \
            if (!(DIAGM) || mt <= nt) {                                                 \
                _Pragma("unroll")                                                       \
                for (int ks = 0; ks < 2; ++ks)                                          \
                    st[mt][nt] = MFMA16(ak[ks], qf[nt][ks], st[mt][nt]);                \
            }                                                                           \
    }                                                                                   \
    _Pragma("unroll")                                                                   \
    for (int nt = 0; nt < 4; ++nt) {                                                    \
        float mloc = -1e30f;                                                            \
        _Pragma("unroll")                                                               \
        for (int mt = 0; mt < 4; ++mt) {                                                \
            if ((DIAGM) && mt > nt) continue;                                           \
            _Pragma("unroll")                                                           \
            for (int i = 0; i < 4; ++i) {                                               \
                float sv = st[mt][nt][i];                                               \
                if ((DIAGM) && mt == nt) {        /* kv0==q0: mask is 4g+i <= lr */     \
                    sv = (4 * g + i <= lr) ? sv : -1e30f;                               \
                    st[mt][nt][i] = sv;                                                 \
                }                                                                       \
                mloc = fmaxf(mloc, sv);                                                 \
            }                                                                           \
        }                                                                               \
        mloc = fmaxf(mloc, __shfl_xor(mloc, 16));                                       \
        mloc = fmaxf(mloc, __shfl_xor(mloc, 32));                                       \
        if (__any(mloc > mrun[nt] + 8.0f)) {       /* defer-max */                      \
            float mnew = fmaxf(mrun[nt], mloc);                                         \
            float sc = exp2f(mrun[nt] - mnew);                                          \
            lsum[nt] *= sc;                                                             \
            _Pragma("unroll")                                                           \
            for (int mo = 0; mo < 4; ++mo)                                              \
                _Pragma("unroll")                                                       \
                for (int i = 0; i < 4; ++i) o[mo][nt][i] *= sc;                         \
            mrun[nt] = mnew;                                                            \
        }                                                                               \
        float ls = 0.f;                                                                 \
        _Pragma("unroll")                                                               \
        for (int mt = 0; mt < 4; ++mt) {                                                \
            f16x4 pk;                                                                   \
            if ((DIAGM) && mt > nt) {                                                   \
                pk[0] = pk[1] = pk[2] = pk[3] = (f16)0.f;                               \
            } else {                                                                    \
                _Pragma("unroll")                                                       \
                for (int i = 0; i < 4; ++i) {                                           \
                    float p = exp2f(st[mt][nt][i] - mrun[nt]);                          \
                    ls += p; pk[i] = (f16)p;                                            \
                }                                                                       \
            }                                                                           \
            *reinterpret_cast<f16x4*>(&lp[nt * 16 + lr][mt * 16 + 4 * g]) = pk;         \
        }                                                                               \
        lsum[nt] += ls;                                                                 \
    }                                                                                   \
    {                                                                                   \
        f16x8 pf[4][2];                                                                 \
        _Pragma("unroll")                                                               \
        for (int nt = 0; nt < 4; ++nt)                                                  \
            _Pragma("unroll")                                                           \
            for (int ks = 0; ks < 2; ++ks)                                              \
                pf[nt][ks] = *reinterpret_cast<const f16x8*>(                           \
                    &lp[nt * 16 + lr][ks * 32 + g * 8]);                                \
        _Pragma("unroll")                                                               \
        for (int mo = 0; mo < 4; ++mo) {                                                \
            f16x8 av[2];                                                                \
            _Pragma("unroll")                                                           \
            for (int ks = 0; ks < 2; ++ks)                                              \
                av[ks] = *reinterpret_cast<const f16x8*>(                               \
                    &Vb[(size_t)(mo * 16 + lr) * 2048 + kv0_ + ks * 32 + g * 8]);       \
            _Pragma("unroll")                                                           \
            for (int nt = 0; nt < 4; ++nt)                                              \
                _Pragma("unroll")                                                       \
                for (int ks = 0; ks < 2; ++ks)                                          \
                    o[mo][nt] = MFMA16(av[ks], pf[nt][ks], o[mo][nt]);                  \
        }                                                                               \
    }                                                                                   \
} while (0)

    const int tEnd = start + len - (diag ? 1 : 0);
    for (int tt = start; tt < tEnd; ++tt)
        ATTN_TILE(tt << 6, 0);                     // full tiles
    if (diag)
        ATTN_TILE((ntt - 1) << 6, 1);              // diagonal tile, triangular
#undef ATTN_TILE

    // epilogue
    const bool split = (u >= 10);
    f16* osl = nullptr; int G = 0;
    if (split) {
        G = bh * 104 + unit_psl(u) + c;            // global slot, [0, 3328)
        osl = (G < 2048) ? op0 + (size_t)G * 4096
            : (G < 2816) ? op1 + (size_t)(G - 2048) * 4096
            :              op2 + (size_t)(G - 2816) * 4096;
    }
    #pragma unroll
    for (int nt = 0; nt < 4; ++nt) {
        float l = lsum[nt];
        l += __shfl_xor(l, 16);
        l += __shfl_xor(l, 32);
        const float inv = 1.0f / l;
        const int lrow = nt * 16 + lr;             // local q row (0..63)
        if (!split) {
            const size_t rowoff = ((size_t)(b * 2048 + q0 + lrow)) * 1024 + h * 64;
            #pragma unroll
            for (int mo = 0; mo < 4; ++mo) {
                f16x4 ov;
                #pragma unroll
                for (int i2 = 0; i2 < 4; ++i2) ov[i2] = (f16)(o[mo][nt][i2] * inv);
                *reinterpret_cast<f16x4*>(&ctx[rowoff + mo * 16 + 4 * g]) = ov;
            }
        } else {
            #pragma unroll
            for (int mo = 0; mo < 4; ++mo) {
                f16x4 ov;
                #pragma unroll
                for (int i2 = 0; i2 < 4; ++i2) ov[i2] = (f16)(o[mo][nt][i2] * inv);
                *reinterpret_cast<f16x4*>(&osl[lrow * 64 + mo * 16 + 4 * g]) = ov;
            }
            if (g == 0) { mpart[G * 64 + lrow] = mrun[nt]; lpart[G * 64 + lrow] = l; }
        }
    }
}

// ---------------------------------------------------------------- combine partials -> ctx
// 704 blocks = (bh 32) x (u 10..31); nc = 3..7. 256 threads: lrow=t>>2 (0..63), seg=t&3.
__global__ __launch_bounds__(256) void combine_k(
    const f16* __restrict__ op0, const f16* __restrict__ op1, const f16* __restrict__ op2,
    const float* __restrict__ mpart, const float* __restrict__ lpart, f16* __restrict__ ctx)
{
    const int blk = blockIdx.x;
    const int bh = blk & 31, u = 10 + (blk >> 5);
    const int b = bh >> 4, h = bh & 15;
    const int nc = (u + 5) / 5;                    // 3..7
    const int G0 = bh * 104 + unit_psl(u);
    const int t = threadIdx.x;
    const int lrow = t >> 2, seg = t & 3;

    float m[7], l[7], w[7];
    float M = -1e30f;
    #pragma unroll
    for (int cc = 0; cc < 7; ++cc) if (cc < nc) {
        m[cc] = mpart[(G0 + cc) * 64 + lrow];
        l[cc] = lpart[(G0 + cc) * 64 + lrow];
        M = fmaxf(M, m[cc]);
    }
    float wsum = 0.f;
    #pragma unroll
    for (int cc = 0; cc < 7; ++cc) if (cc < nc) { w[cc] = l[cc] * exp2f(m[cc] - M); wsum += w[cc]; }
    const float r = 1.0f / wsum;

    float acc[16] = {};
    #pragma unroll
    for (int cc = 0; cc < 7; ++cc) if (cc < nc) {
        const int G = G0 + cc;
        const f16* osl = (G < 2048) ? op0 + (size_t)G * 4096
                       : (G < 2816) ? op1 + (size_t)(G - 2048) * 4096
                       :              op2 + (size_t)(G - 2816) * 4096;
        const float coef = w[cc] * r;
        f16x8 v0 = *reinterpret_cast<const f16x8*>(&osl[lrow * 64 + seg * 16]);
        f16x8 v1 = *reinterpret_cast<const f16x8*>(&osl[lrow * 64 + seg * 16 + 8]);
        #pragma unroll
        for (int i = 0; i < 8; ++i) { acc[i] += coef * (float)v0[i]; acc[i + 8] += coef * (float)v1[i]; }
    }
    f16x8 o0, o1;
    #pragma unroll
    for (int i = 0; i < 8; ++i) { o0[i] = (f16)acc[i]; o1[i] = (f16)acc[i + 8]; }
    const size_t wb = ((size_t)(b * 2048 + u * 64 + lrow)) * 1024 + h * 64 + seg * 16;
    *reinterpret_cast<f16x8*>(&ctx[wb]) = o0;
    *reinterpret_cast<f16x8*>(&ctx[wb + 8]) = o1;
}

// ---------------------------------------------------------------- launch
extern "C" void kernel_launch(void* const* d_in, const int* in_sizes, int n_in,
                              void* d_out, int out_size, void* d_ws, size_t ws_size,
                              hipStream_t stream) {
    const float* x      = (const float*)d_in[0];   // [2,2048,1024]
    const float* w_qkv  = (const float*)d_in[1];   // [3072,1024]
    const float* w_proj = (const float*)d_in[2];   // [1024,1024]
    const float* b_proj = (const float*)d_in[3];   // [1024]
    float* out = (float*)d_out;                    // [2,2048,1024] fp32

    char* p = (char*)d_ws;
    f16* xh     = (f16*)p; p += (size_t)4096 * 1024 * 2;        // 8 MB (dead after gemm0: op2+m/l)
    f16* wqkvh  = (f16*)p; p += (size_t)3072 * 1024 * 2;        // 6 MB (dead after gemm0: op1)
    f16* wprojh = (f16*)p; p += (size_t)1024 * 1024 * 2;        // 2 MB (live through gemm1)
    f16* qbuf   = (f16*)p; p += (size_t)2 * 16 * 2048 * 64 * 2; // 8 MB  [B,H,S,64], pre-scaled
    f16* kbuf   = (f16*)p; p += (size_t)2 * 16 * 2048 * 64 * 2; // 8 MB  [B,H,S,64]
    f16* vtbuf  = (f16*)p; p += (size_t)2 * 16 * 64 * 2048 * 2; // 8 MB  [B,H,64,S] transposed
    f16* ctx    = (f16*)p; p += (size_t)4096 * 1024 * 2;        // 8 MB  (total 48 MB)

    // Partial-O slots (8192 B each = 64 rows x 64 f16): 3328 needed.
    //   op0 = d_out          : 2048 slots (16.78 MB, dead until gemm1 writes it)
    //   op1 = wqkvh          :  768 slots (6 MB, dead after gemm0)
    //   op2 = xh[0 .. 6MB)   :  768 slots (dead after gemm0)
    //   mpart/lpart = xh + 6MB (852 KB each; 6MB + 1.7MB < 8MB)
    f16*   op0 = (f16*)d_out;
    f16*   op1 = wqkvh;
    f16*   op2 = xh;
    float* mpart = (float*)(xh + (size_t)3145728);   // xh + 6 MB
    float* lpart = mpart + 212992;                   // 3328 * 64

    cvt_all<<<8192, 256, 0, stream>>>(x, w_qkv, w_proj, xh, wqkvh, wprojh);

    gemm_k<0, 128><<<dim3(24, 32), 256, 0, stream>>>(xh, wqkvh, 1024, qbuf, kbuf, vtbuf, nullptr, nullptr);

    attn_k<<<3648, 64, 0, stream>>>(qbuf, kbuf, vtbuf, ctx, op0, op1, op2, mpart, lpart);

    combine_k<<<704, 256, 0, stream>>>(op0, op1, op2, mpart, lpart, ctx);

    gemm_k<1, 64><<<dim3(16, 32), 256, 0, stream>>>(ctx, wprojh, 1024, nullptr, nullptr, nullptr, out, b_proj);
}